// Round 4
// baseline (414.138 us; speedup 1.0000x reference)
//
#include <hip/hip_runtime.h>

#define NFEAT 128
#define DOUT 48
#define BSH 6                 // 64 nodes per bucket
#define BNODES (1 << BSH)
#define CAP 2048              // LDS edge capacity per bucket (mean 1024, sigma 32)

// ---------------- kernel A: h = feat @ W^T + b ; s_src/s_dst dots ----------------
__global__ __launch_bounds__(256) void k_proj(
    const float* __restrict__ feat, const float* __restrict__ Ww,
    const float* __restrict__ Wb, const float* __restrict__ attn_w,
    float* __restrict__ h, float* __restrict__ s_src, float* __restrict__ s_dst,
    int n)
{
    int node = blockIdx.x * 256 + threadIdx.x;
    if (node >= n) return;

    float hv[DOUT];
#pragma unroll
    for (int j = 0; j < DOUT; ++j) hv[j] = Wb[j];

    const float4* fp = (const float4*)(feat + (size_t)node * NFEAT);
#pragma unroll 1
    for (int c = 0; c < 4; ++c) {
        float4 f[8];
#pragma unroll
        for (int i = 0; i < 8; ++i) f[i] = fp[c * 8 + i];
#pragma unroll 1
        for (int j = 0; j < DOUT; ++j) {
            const float4* wp = (const float4*)(Ww + (size_t)j * NFEAT + c * 32);  // wave-uniform
            float acc = hv[j];
#pragma unroll
            for (int i = 0; i < 8; ++i) {
                float4 w = wp[i];
                acc = fmaf(f[i].x, w.x, acc);
                acc = fmaf(f[i].y, w.y, acc);
                acc = fmaf(f[i].z, w.z, acc);
                acc = fmaf(f[i].w, w.w, acc);
            }
            hv[j] = acc;
        }
    }

    float ss = 0.f, sd = 0.f;
#pragma unroll
    for (int j = 0; j < DOUT; ++j) {
        ss = fmaf(hv[j], attn_w[j], ss);
        sd = fmaf(hv[j], attn_w[DOUT + j], sd);
    }

    float4* hp = (float4*)(h + (size_t)node * DOUT);
#pragma unroll
    for (int i = 0; i < DOUT / 4; ++i)
        hp[i] = make_float4(hv[4 * i], hv[4 * i + 1], hv[4 * i + 2], hv[4 * i + 3]);
    s_src[node] = ss;
    s_dst[node] = sd;
}

// ---------------- bucket histogram per (bucket, class) ----------------
// class = blockIdx & 7 must use the SAME edge->block mapping as k_bin.
__global__ __launch_bounds__(256) void k_bhist(
    const int* __restrict__ dst, int* __restrict__ bh, int nE)
{
    int e = blockIdx.x * 256 + threadIdx.x;
    if (e >= nE) return;
    int d = dst[e];
    atomicAdd(bh + ((d >> BSH) * 8 + (blockIdx.x & 7)), 1);
}

// ---------------- single-block exclusive scan over N8 counters ----------------
__global__ __launch_bounds__(256) void k_scanb(
    const int* __restrict__ bh, int* __restrict__ base, int* __restrict__ cursor, int N)
{
    __shared__ int part[256];
    int t = threadIdx.x;
    int chunk = (N + 255) / 256;
    int lo = t * chunk, hi = min(lo + chunk, N);
    int s = 0;
    for (int i = lo; i < hi; ++i) s += bh[i];
    part[t] = s;
    __syncthreads();
#pragma unroll
    for (int off = 1; off < 256; off <<= 1) {
        int v = (t >= off) ? part[t - off] : 0;
        __syncthreads();
        part[t] += v;
        __syncthreads();
    }
    int run = part[t] - s;  // exclusive prefix of this chunk
    for (int i = lo; i < hi; ++i) {
        base[i] = run;
        cursor[i] = run;
        run += bh[i];
    }
    if (t == 255) base[N] = run;
}

// ---------------- bin edges: scatter (src|d_local, exp(lrelu)) into sub-regions ----------------
__global__ __launch_bounds__(256) void k_bin(
    const int* __restrict__ src, const int* __restrict__ dst,
    const float* __restrict__ s_src, const float* __restrict__ s_dst,
    const float* __restrict__ attn_b,
    int* __restrict__ cursor, int2* __restrict__ ents, int nE)
{
    int e = blockIdx.x * 256 + threadIdx.x;
    if (e >= nE) return;
    int d = dst[e];
    int s = src[e];
    float v = s_src[s] + s_dst[d] + attn_b[0];
    v = (v > 0.f) ? v : 0.2f * v;               // leaky_relu(0.2)
    float x = __expf(v);                        // softmax shift-invariant: no max needed
    int slot = atomicAdd(cursor + ((d >> BSH) * 8 + (blockIdx.x & 7)), 1);
    ents[slot] = make_int2(s | ((d & (BNODES - 1)) << 17), __float_as_int(x));
}

// ---------------- fused LDS-sort + softmax-aggregate: one block per bucket ----------------
__global__ __launch_bounds__(256) void k_aggb(
    const float* __restrict__ h, const int* __restrict__ base,
    const int2* __restrict__ ents, float* __restrict__ out, int n)
{
    __shared__ int2 se[CAP];
    __shared__ unsigned short sidx[CAP];
    __shared__ int c1[BNODES], c2[BNODES], lrp[BNODES + 1];

    int b = blockIdx.x;
    int tid = threadIdx.x;
    int r0 = base[b * 8], r1 = base[b * 8 + 8];
    int cnt = min(r1 - r0, CAP);

    if (tid < BNODES) { c1[tid] = 0; c2[tid] = 0; }
    __syncthreads();

    // load region into LDS + per-node counts
    for (int i = tid; i < cnt; i += 256) {
        int2 v = ents[r0 + i];
        se[i] = v;
        atomicAdd(&c1[((unsigned)v.x) >> 17], 1);
    }
    __syncthreads();

    // wave 0: exclusive scan of 64 counts
    if (tid < BNODES) {
        int v = c1[tid];
        int p = v;
#pragma unroll
        for (int o = 1; o < 64; o <<= 1) {
            int u = __shfl_up(p, o, 64);
            if (tid >= o) p += u;
        }
        lrp[tid] = p - v;
        if (tid == BNODES - 1) lrp[BNODES] = p;
    }
    __syncthreads();

    // counting-sort indices by d_local
    for (int i = tid; i < cnt; i += 256) {
        int dl = ((unsigned)se[i].x) >> 17;
        int pos = lrp[dl] + atomicAdd(&c2[dl], 1);
        sidx[pos] = (unsigned short)i;
    }
    __syncthreads();

    // aggregate: wave per node round-robin, 4 groups of 16 lanes per wave
    int wave = tid >> 6, lane = tid & 63;
    int g = lane >> 4, sub = lane & 15;
    for (int dl = wave; dl < BNODES; dl += 4) {
        int node = (b << BSH) + dl;
        if (node >= n) break;
        int st = lrp[dl], en = lrp[dl + 1];
        float a0 = 0.f, a1 = 0.f, a2 = 0.f, den = 0.f;
        for (int k = st + g; k < en; k += 4) {
            int2 ed = se[sidx[k]];                 // 16 lanes same addr -> LDS broadcast
            float x = __int_as_float(ed.y);
            den += x;
            const float* hr = h + (size_t)(ed.x & 0x1FFFF) * DOUT + sub * 3;
            a0 = fmaf(x, hr[0], a0);
            a1 = fmaf(x, hr[1], a1);
            a2 = fmaf(x, hr[2], a2);
        }
#pragma unroll
        for (int o = 16; o <= 32; o <<= 1) {
            a0  += __shfl_xor(a0, o, 64);
            a1  += __shfl_xor(a1, o, 64);
            a2  += __shfl_xor(a2, o, 64);
            den += __shfl_xor(den, o, 64);
        }
        if (lane < 16) {
            float inv = (en > st) ? 1.f / den : 0.f;
            float* op = out + (size_t)node * DOUT + sub * 3;
            op[0] = a0 * inv;
            op[1] = a1 * inv;
            op[2] = a2 * inv;
        }
    }
}

extern "C" void kernel_launch(void* const* d_in, const int* in_sizes, int n_in,
                              void* d_out, int out_size, void* d_ws, size_t ws_size,
                              hipStream_t stream) {
    const float* feat   = (const float*)d_in[0];
    const float* Ww     = (const float*)d_in[1];
    const float* Wb     = (const float*)d_in[2];
    const float* attn_w = (const float*)d_in[3];
    const float* attn_b = (const float*)d_in[4];
    const int*   src    = (const int*)d_in[5];
    const int*   dst    = (const int*)d_in[6];

    int n  = in_sizes[0] / NFEAT;          // 100000
    int nE = in_sizes[5];                  // 1600000
    int NB = (n + BNODES - 1) / BNODES;    // 1563 buckets
    int N8 = NB * 8;                       // (bucket, class) counters
    float* out = (float*)d_out;

    // workspace layout
    float* ws     = (float*)d_ws;
    float* h      = ws;                          // n*48
    float* s_src  = h + (size_t)n * DOUT;        // n
    float* s_dst  = s_src + n;                   // n
    int*   bh     = (int*)(s_dst + n);           // N8
    int*   base   = bh + N8;                     // N8+1
    int*   cursor = base + N8 + 1;               // N8
    int2*  ents   = (int2*)(cursor + N8);        // nE

    hipMemsetAsync(bh, 0, (size_t)N8 * sizeof(int), stream);

    k_proj<<<(n + 255) / 256, 256, 0, stream>>>(feat, Ww, Wb, attn_w, h, s_src, s_dst, n);
    k_bhist<<<(nE + 255) / 256, 256, 0, stream>>>(dst, bh, nE);
    k_scanb<<<1, 256, 0, stream>>>(bh, base, cursor, N8);
    k_bin<<<(nE + 255) / 256, 256, 0, stream>>>(src, dst, s_src, s_dst, attn_b, cursor, ents, nE);
    k_aggb<<<NB, 256, 0, stream>>>(h, base, ents, out, n);
}